// Round 1
// baseline (675.220 us; speedup 1.0000x reference)
//
#include <hip/hip_runtime.h>
#include <math.h>

#define L_SEQ 1024
#define HE 512          // H*E
#define NBATCH 32
#define TOPK 6
#define NZ 8            // K-split factor (batch groups of 4)

// ---------------------------------------------------------------------------
// Kernel 1: partial Gram matrices.
// Gz[z][s][t] = sum_{b in z-group, he} q[b,s,he] * k[b,t,he]
// grid (16,16,NZ), block 256. 64x64 tile, 4x4 per thread (cols strided by 16).
// ---------------------------------------------------------------------------
__global__ __launch_bounds__(256) void gram_kernel(
    const float* __restrict__ q, const float* __restrict__ k,
    float* __restrict__ Gz)
{
  __shared__ float As[64][18];   // pad 18: conflict-free float2 frag reads
  __shared__ float Bs[64][18];
  const int s0 = blockIdx.x * 64;
  const int t0 = blockIdx.y * 64;
  const int z  = blockIdx.z;
  const int tid = threadIdx.x;
  const int tx = tid & 15, ty = tid >> 4;
  const int lr = tid >> 2;          // staging row 0..63
  const int lc = (tid & 3) << 2;    // staging col 0,4,8,12

  float acc[4][4] = {{0.f, 0.f, 0.f, 0.f}, {0.f, 0.f, 0.f, 0.f},
                     {0.f, 0.f, 0.f, 0.f}, {0.f, 0.f, 0.f, 0.f}};

  for (int b = z * 4; b < z * 4 + 4; ++b) {
    const float* qrow = q + ((size_t)b * L_SEQ + s0 + lr) * HE + lc;
    const float* krow = k + ((size_t)b * L_SEQ + t0 + lr) * HE + lc;
    for (int he0 = 0; he0 < HE; he0 += 16) {
      const float4 av = *(const float4*)(qrow + he0);
      const float4 bv = *(const float4*)(krow + he0);
      __syncthreads();
      As[lr][lc + 0] = av.x; As[lr][lc + 1] = av.y;
      As[lr][lc + 2] = av.z; As[lr][lc + 3] = av.w;
      Bs[lr][lc + 0] = bv.x; Bs[lr][lc + 1] = bv.y;
      Bs[lr][lc + 2] = bv.z; Bs[lr][lc + 3] = bv.w;
      __syncthreads();
      #pragma unroll
      for (int kk = 0; kk < 16; kk += 2) {
        const float2 a0 = *(const float2*)&As[ty * 4 + 0][kk];
        const float2 a1 = *(const float2*)&As[ty * 4 + 1][kk];
        const float2 a2 = *(const float2*)&As[ty * 4 + 2][kk];
        const float2 a3 = *(const float2*)&As[ty * 4 + 3][kk];
        const float2 b0 = *(const float2*)&Bs[tx + 0][kk];
        const float2 b1 = *(const float2*)&Bs[tx + 16][kk];
        const float2 b2 = *(const float2*)&Bs[tx + 32][kk];
        const float2 b3 = *(const float2*)&Bs[tx + 48][kk];
        acc[0][0] += a0.x * b0.x; acc[0][0] += a0.y * b0.y;
        acc[0][1] += a0.x * b1.x; acc[0][1] += a0.y * b1.y;
        acc[0][2] += a0.x * b2.x; acc[0][2] += a0.y * b2.y;
        acc[0][3] += a0.x * b3.x; acc[0][3] += a0.y * b3.y;
        acc[1][0] += a1.x * b0.x; acc[1][0] += a1.y * b0.y;
        acc[1][1] += a1.x * b1.x; acc[1][1] += a1.y * b1.y;
        acc[1][2] += a1.x * b2.x; acc[1][2] += a1.y * b2.y;
        acc[1][3] += a1.x * b3.x; acc[1][3] += a1.y * b3.y;
        acc[2][0] += a2.x * b0.x; acc[2][0] += a2.y * b0.y;
        acc[2][1] += a2.x * b1.x; acc[2][1] += a2.y * b1.y;
        acc[2][2] += a2.x * b2.x; acc[2][2] += a2.y * b2.y;
        acc[2][3] += a2.x * b3.x; acc[2][3] += a2.y * b3.y;
        acc[3][0] += a3.x * b0.x; acc[3][0] += a3.y * b0.y;
        acc[3][1] += a3.x * b1.x; acc[3][1] += a3.y * b1.y;
        acc[3][2] += a3.x * b2.x; acc[3][2] += a3.y * b2.y;
        acc[3][3] += a3.x * b3.x; acc[3][3] += a3.y * b3.y;
      }
    }
  }

  float* Gp = Gz + (size_t)z * L_SEQ * L_SEQ;
  #pragma unroll
  for (int i = 0; i < 4; ++i) {
    #pragma unroll
    for (int j = 0; j < 4; ++j) {
      Gp[(size_t)(s0 + ty * 4 + i) * L_SEQ + (t0 + tx + 16 * j)] = acc[i][j];
    }
  }
}

// ---------------------------------------------------------------------------
// Kernel 2: c[tau] = (1/16384) * sum_z sum_t Gz[z][(t+tau)%L][t]
// grid 1024 (one block per tau), block 256.
// ---------------------------------------------------------------------------
__global__ __launch_bounds__(256) void diag_kernel(
    const float* __restrict__ G, float* __restrict__ c)
{
  const int tau = blockIdx.x;
  const int tid = threadIdx.x;
  float s = 0.f;
  for (int t = tid; t < L_SEQ; t += 256) {
    const int row = (t + tau) & (L_SEQ - 1);
    const size_t off = (size_t)row * L_SEQ + t;
    #pragma unroll
    for (int z = 0; z < NZ; ++z)
      s += G[(size_t)z * L_SEQ * L_SEQ + off];
  }
  #pragma unroll
  for (int o = 32; o > 0; o >>= 1) s += __shfl_down(s, o, 64);
  __shared__ float wsum[4];
  if ((tid & 63) == 0) wsum[tid >> 6] = s;
  __syncthreads();
  if (tid == 0)
    c[tau] = (wsum[0] + wsum[1] + wsum[2] + wsum[3]) * (1.0f / 16384.0f);
}

// ---------------------------------------------------------------------------
// Kernel 3: top-6 (descending, smaller-index tie-break like lax.top_k)
// + softmax over the 6 values. 1 block, 256 threads.
// ---------------------------------------------------------------------------
__global__ __launch_bounds__(256) void topk_kernel(
    const float* __restrict__ c, int* __restrict__ idx_out,
    float* __restrict__ w_out)
{
  __shared__ float vals[L_SEQ];
  __shared__ float rv[256];
  __shared__ int ri[256];
  __shared__ float topv[TOPK];
  __shared__ int topi[TOPK];
  const int tid = threadIdx.x;
  for (int i = tid; i < L_SEQ; i += 256) vals[i] = c[i];
  __syncthreads();

  for (int kk = 0; kk < TOPK; ++kk) {
    float bv = -INFINITY;
    int bi = 1 << 30;
    for (int i = tid; i < L_SEQ; i += 256) {
      const float v = vals[i];
      if (v > bv || (v == bv && i < bi)) { bv = v; bi = i; }
    }
    rv[tid] = bv; ri[tid] = bi;
    __syncthreads();
    for (int off = 128; off > 0; off >>= 1) {
      if (tid < off) {
        const float v2 = rv[tid + off];
        const int i2 = ri[tid + off];
        if (v2 > rv[tid] || (v2 == rv[tid] && i2 < ri[tid])) {
          rv[tid] = v2; ri[tid] = i2;
        }
      }
      __syncthreads();
    }
    if (tid == 0) {
      topv[kk] = rv[0];
      topi[kk] = ri[0];
      vals[ri[0]] = -INFINITY;
    }
    __syncthreads();
  }

  if (tid == 0) {
    const float m = topv[0];
    float e[TOPK], sum = 0.f;
    for (int i = 0; i < TOPK; ++i) { e[i] = expf(topv[i] - m); sum += e[i]; }
    const float inv = 1.0f / sum;
    for (int i = 0; i < TOPK; ++i) { w_out[i] = e[i] * inv; idx_out[i] = topi[i]; }
  }
}

// ---------------------------------------------------------------------------
// Kernel 4: out[b,l,h,e] = sum_k w[k] * v[b,(l+idx[k])%L,h,e]
// float4 over the (h,e) dim. grid 16384, block 256 -> exactly 2^22 float4.
// ---------------------------------------------------------------------------
__global__ __launch_bounds__(256) void agg_kernel(
    const float* __restrict__ v, const int* __restrict__ idx,
    const float* __restrict__ w, float4* __restrict__ out)
{
  __shared__ int sidx[TOPK];
  __shared__ float sw[TOPK];
  if (threadIdx.x < TOPK) {
    sidx[threadIdx.x] = idx[threadIdx.x];
    sw[threadIdx.x] = w[threadIdx.x];
  }
  __syncthreads();

  const int i = blockIdx.x * 256 + threadIdx.x;   // 0 .. 2^22-1
  const int he4 = i & 127;                        // 512/4
  const int l = (i >> 7) & (L_SEQ - 1);
  const int b = i >> 17;
  const float4* vb = (const float4*)v + (size_t)b * (L_SEQ * 128);

  float4 acc = make_float4(0.f, 0.f, 0.f, 0.f);
  #pragma unroll
  for (int kk = 0; kk < TOPK; ++kk) {
    const int src = (l + sidx[kk]) & (L_SEQ - 1);
    const float4 vv = vb[(size_t)src * 128 + he4];
    const float wk = sw[kk];
    acc.x += wk * vv.x; acc.y += wk * vv.y;
    acc.z += wk * vv.z; acc.w += wk * vv.w;
  }
  out[i] = acc;
}

// ---------------------------------------------------------------------------
extern "C" void kernel_launch(void* const* d_in, const int* in_sizes, int n_in,
                              void* d_out, int out_size, void* d_ws, size_t ws_size,
                              hipStream_t stream) {
  const float* q = (const float*)d_in[0];
  const float* k = (const float*)d_in[1];
  const float* v = (const float*)d_in[2];
  // d_in[3] = attn_mask (scalar 0) -- unused

  float* out = (float*)d_out;
  // Stage the 8 partial Gram buffers (8 * 4 MB = 32 MB) at the front of
  // d_out (67 MB); they are fully consumed by diag_kernel before agg_kernel
  // overwrites all of d_out. Deterministic (no atomics).
  float* Gz = out;

  float* c = (float*)d_ws;                              // 1024 floats
  int* idxp = (int*)((char*)d_ws + 4096);               // 6 ints
  float* wp = (float*)((char*)d_ws + 4096 + 64);        // 6 floats

  dim3 gGram(L_SEQ / 64, L_SEQ / 64, NZ);
  gram_kernel<<<gGram, 256, 0, stream>>>(q, k, Gz);
  diag_kernel<<<L_SEQ, 256, 0, stream>>>(Gz, c);
  topk_kernel<<<1, 256, 0, stream>>>(c, idxp, wp);
  agg_kernel<<<(L_SEQ * NBATCH * 128) / 256, 256, 0, stream>>>(v, idxp, wp,
                                                               (float4*)out);
}

// Round 2
// 250.444 us; speedup vs baseline: 2.6961x; 2.6961x over previous
//
#include <hip/hip_runtime.h>
#include <math.h>

#define L_SEQ 1024
#define HE 512          // H*E
#define NBATCH 32
#define TOPK 6
#define NZ 16           // K-split factor (2 batches = K-chunk of 1024 per slice)

using bf16x8 = __attribute__((ext_vector_type(8))) short;
using f32x4  = __attribute__((ext_vector_type(4))) float;

// pack two fp32 -> two bf16 (RNE) in one uint
__device__ __forceinline__ unsigned int bf2(float lo, float hi) {
  unsigned int ul = __float_as_uint(lo);
  unsigned int uh = __float_as_uint(hi);
  ul += 0x7fffu + ((ul >> 16) & 1u);
  uh += 0x7fffu + ((uh >> 16) & 1u);
  return (ul >> 16) | (uh & 0xffff0000u);
}

// ---------------------------------------------------------------------------
// Kernel 1: partial Gram via bf16 MFMA, fp32 accumulate.
// Gz[z][s][t] = sum_{b in z-group(2), he} q[b,s,he] * k[b,t,he]
// grid (8,8,NZ), block 256 (4 waves, 2x2 over a 128x128 tile), BK=64.
// LDS tiles XOR-swizzled: byte ^= (row&7)<<4  (conflict-free b128 access).
// ---------------------------------------------------------------------------
__global__ __launch_bounds__(256) void gram_bf16_kernel(
    const float* __restrict__ q, const float* __restrict__ k,
    float* __restrict__ Gz)
{
  __shared__ unsigned int As[128 * 64 / 2];   // 16 KB (bf16 pairs)
  __shared__ unsigned int Bs[128 * 64 / 2];   // 16 KB

  const int tid = threadIdx.x;
  const int l   = tid & 63;
  const int wid = tid >> 6;
  const int wr  = (wid >> 1) * 64;   // wave row offset in tile
  const int wc  = (wid & 1) * 64;    // wave col offset in tile
  const int s0  = blockIdx.x * 128;
  const int t0  = blockIdx.y * 128;
  const int z   = blockIdx.z;

  // staging chunk ids: it in 0..3, id = it*256+tid -> (row 0..127, c8 0..7)
  int srow[4], swoff[4];             // LDS byte offset (swizzled)
  size_t agoff[4], bgoff[4];         // global float offsets (row part)
  #pragma unroll
  for (int it = 0; it < 4; ++it) {
    const int id  = (it << 8) | tid;
    const int row = id >> 3;
    const int c8  = id & 7;
    srow[it]  = row;
    swoff[it] = ((row << 7) + (c8 << 4)) ^ ((row & 7) << 4);
    agoff[it] = (size_t)(s0 + row) * HE + c8 * 8;
    bgoff[it] = (size_t)(t0 + row) * HE + c8 * 8;
  }

  f32x4 acc[4][4] = {};

  const int l15 = l & 15;
  const int blk = l >> 4;

  for (int t = 0; t < 16; ++t) {              // K per block = 1024, BK=64
    const int kt = t * 64;
    const size_t boff = ((size_t)(z * 2 + (kt >> 9)) * L_SEQ) * HE + (kt & 511);

    // global fp32 loads + convert to packed bf16
    uint4 pa[4], pb[4];
    #pragma unroll
    for (int it = 0; it < 4; ++it) {
      const float4 a0 = *(const float4*)(q + boff + agoff[it]);
      const float4 a1 = *(const float4*)(q + boff + agoff[it] + 4);
      const float4 b0 = *(const float4*)(k + boff + bgoff[it]);
      const float4 b1 = *(const float4*)(k + boff + bgoff[it] + 4);
      pa[it].x = bf2(a0.x, a0.y); pa[it].y = bf2(a0.z, a0.w);
      pa[it].z = bf2(a1.x, a1.y); pa[it].w = bf2(a1.z, a1.w);
      pb[it].x = bf2(b0.x, b0.y); pb[it].y = bf2(b0.z, b0.w);
      pb[it].z = bf2(b1.x, b1.y); pb[it].w = bf2(b1.z, b1.w);
    }

    __syncthreads();   // previous tile's reads done
    #pragma unroll
    for (int it = 0; it < 4; ++it) {
      *(uint4*)((char*)As + swoff[it]) = pa[it];
      *(uint4*)((char*)Bs + swoff[it]) = pb[it];
    }
    __syncthreads();   // tile staged

    #pragma unroll
    for (int kk = 0; kk < 2; ++kk) {
      bf16x8 af[4], bf[4];
      #pragma unroll
      for (int m = 0; m < 4; ++m) {
        const int rowa = wr + m * 16 + l15;
        const int offa = ((rowa << 7) + (kk << 6) + (blk << 4)) ^ ((rowa & 7) << 4);
        af[m] = *(const bf16x8*)((const char*)As + offa);
        const int rowb = wc + m * 16 + l15;
        const int offb = ((rowb << 7) + (kk << 6) + (blk << 4)) ^ ((rowb & 7) << 4);
        bf[m] = *(const bf16x8*)((const char*)Bs + offb);
      }
      #pragma unroll
      for (int m = 0; m < 4; ++m)
        #pragma unroll
        for (int n = 0; n < 4; ++n)
          acc[m][n] = __builtin_amdgcn_mfma_f32_16x16x32_bf16(
              af[m], bf[n], acc[m][n], 0, 0, 0);
    }
  }

  // C/D layout: col = lane&15, row = (lane>>4)*4 + reg   [m89/m91 verified]
  float* Gp = Gz + (size_t)z * L_SEQ * L_SEQ;
  const int crow = s0 + wr + blk * 4;
  const int ccol = t0 + wc + l15;
  #pragma unroll
  for (int m = 0; m < 4; ++m)
    #pragma unroll
    for (int j = 0; j < 4; ++j) {
      const int rr = crow + m * 16 + j;
      #pragma unroll
      for (int n = 0; n < 4; ++n)
        Gp[(size_t)rr * L_SEQ + ccol + n * 16] = acc[m][n][j];
    }
}

// ---------------------------------------------------------------------------
// Kernel 2: c[tau] = (1/16384) * sum_z sum_t Gz[z][(t+tau)%L][t]
// ---------------------------------------------------------------------------
__global__ __launch_bounds__(256) void diag_kernel(
    const float* __restrict__ G, float* __restrict__ c)
{
  const int tau = blockIdx.x;
  const int tid = threadIdx.x;
  float s = 0.f;
  for (int t = tid; t < L_SEQ; t += 256) {
    const int row = (t + tau) & (L_SEQ - 1);
    const size_t off = (size_t)row * L_SEQ + t;
    #pragma unroll
    for (int z = 0; z < NZ; ++z)
      s += G[(size_t)z * L_SEQ * L_SEQ + off];
  }
  #pragma unroll
  for (int o = 32; o > 0; o >>= 1) s += __shfl_down(s, o, 64);
  __shared__ float wsum[4];
  if ((tid & 63) == 0) wsum[tid >> 6] = s;
  __syncthreads();
  if (tid == 0)
    c[tau] = (wsum[0] + wsum[1] + wsum[2] + wsum[3]) * (1.0f / 16384.0f);
}

// ---------------------------------------------------------------------------
// Kernel 3: top-6 (desc, smaller-index tie-break) + softmax. 1 block.
// ---------------------------------------------------------------------------
__global__ __launch_bounds__(256) void topk_kernel(
    const float* __restrict__ c, int* __restrict__ idx_out,
    float* __restrict__ w_out)
{
  __shared__ float vals[L_SEQ];
  __shared__ float rv[256];
  __shared__ int ri[256];
  __shared__ float topv[TOPK];
  __shared__ int topi[TOPK];
  const int tid = threadIdx.x;
  for (int i = tid; i < L_SEQ; i += 256) vals[i] = c[i];
  __syncthreads();

  for (int kk = 0; kk < TOPK; ++kk) {
    float bv = -INFINITY;
    int bi = 1 << 30;
    for (int i = tid; i < L_SEQ; i += 256) {
      const float v = vals[i];
      if (v > bv || (v == bv && i < bi)) { bv = v; bi = i; }
    }
    rv[tid] = bv; ri[tid] = bi;
    __syncthreads();
    for (int off = 128; off > 0; off >>= 1) {
      if (tid < off) {
        const float v2 = rv[tid + off];
        const int i2 = ri[tid + off];
        if (v2 > rv[tid] || (v2 == rv[tid] && i2 < ri[tid])) {
          rv[tid] = v2; ri[tid] = i2;
        }
      }
      __syncthreads();
    }
    if (tid == 0) {
      topv[kk] = rv[0];
      topi[kk] = ri[0];
      vals[ri[0]] = -INFINITY;
    }
    __syncthreads();
  }

  if (tid == 0) {
    const float m = topv[0];
    float e[TOPK], sum = 0.f;
    for (int i = 0; i < TOPK; ++i) { e[i] = expf(topv[i] - m); sum += e[i]; }
    const float inv = 1.0f / sum;
    for (int i = 0; i < TOPK; ++i) { w_out[i] = e[i] * inv; idx_out[i] = topi[i]; }
  }
}

// ---------------------------------------------------------------------------
// Kernel 4: out[b,l,h,e] = sum_k w[k] * v[b,(l+idx[k])%L,h,e]
// ---------------------------------------------------------------------------
__global__ __launch_bounds__(256) void agg_kernel(
    const float* __restrict__ v, const int* __restrict__ idx,
    const float* __restrict__ w, float4* __restrict__ out)
{
  __shared__ int sidx[TOPK];
  __shared__ float sw[TOPK];
  if (threadIdx.x < TOPK) {
    sidx[threadIdx.x] = idx[threadIdx.x];
    sw[threadIdx.x] = w[threadIdx.x];
  }
  __syncthreads();

  const int i = blockIdx.x * 256 + threadIdx.x;   // 0 .. 2^22-1
  const int he4 = i & 127;                        // 512/4
  const int l = (i >> 7) & (L_SEQ - 1);
  const int b = i >> 17;
  const float4* vb = (const float4*)v + (size_t)b * (L_SEQ * 128);

  float4 acc = make_float4(0.f, 0.f, 0.f, 0.f);
  #pragma unroll
  for (int kk = 0; kk < TOPK; ++kk) {
    const int src = (l + sidx[kk]) & (L_SEQ - 1);
    const float4 vv = vb[(size_t)src * 128 + he4];
    const float wk = sw[kk];
    acc.x += wk * vv.x; acc.y += wk * vv.y;
    acc.z += wk * vv.z; acc.w += wk * vv.w;
  }
  out[i] = acc;
}

// ---------------------------------------------------------------------------
extern "C" void kernel_launch(void* const* d_in, const int* in_sizes, int n_in,
                              void* d_out, int out_size, void* d_ws, size_t ws_size,
                              hipStream_t stream) {
  const float* q = (const float*)d_in[0];
  const float* k = (const float*)d_in[1];
  const float* v = (const float*)d_in[2];
  // d_in[3] = attn_mask (scalar 0) -- unused

  float* out = (float*)d_out;
  // 16 partial Gram slices (16 * 4 MB = 64 MB) exactly fill d_out; they are
  // fully consumed by diag_kernel before agg_kernel overwrites d_out.
  float* Gz = out;

  float* c = (float*)d_ws;                              // 1024 floats
  int* idxp = (int*)((char*)d_ws + 4096);               // 6 ints
  float* wp = (float*)((char*)d_ws + 4096 + 64);        // 6 floats

  dim3 gGram(L_SEQ / 128, L_SEQ / 128, NZ);
  gram_bf16_kernel<<<gGram, 256, 0, stream>>>(q, k, Gz);
  diag_kernel<<<L_SEQ, 256, 0, stream>>>(Gz, c);
  topk_kernel<<<1, 256, 0, stream>>>(c, idxp, wp);
  agg_kernel<<<(L_SEQ * NBATCH * 128) / 256, 256, 0, stream>>>(v, idxp, wp,
                                                               (float4*)out);
}

// Round 3
// 182.000 us; speedup vs baseline: 3.7100x; 1.3761x over previous
//
#include <hip/hip_runtime.h>
#include <math.h>

#define L_SEQ 1024
#define HE 512          // H*E
#define NBATCH 32
#define TOPK 6
#define NZ 16           // K-split: 2 batches = K-chunk of 1024 per slice

using bf16x8 = __attribute__((ext_vector_type(8))) short;
using f32x4  = __attribute__((ext_vector_type(4))) float;

// pack two fp32 -> two bf16 (RNE) in one uint
__device__ __forceinline__ unsigned int bf2(float lo, float hi) {
  unsigned int ul = __float_as_uint(lo);
  unsigned int uh = __float_as_uint(hi);
  ul += 0x7fffu + ((ul >> 16) & 1u);
  uh += 0x7fffu + ((uh >> 16) & 1u);
  return (ul >> 16) | (uh & 0xffff0000u);
}

// ---------------------------------------------------------------------------
// Kernel 1: fused partial-Gram (bf16 MFMA) + per-block diagonal reduction.
// For block (x,y,z): computes 128x128 tile of Gz = q_chunk . k_chunk^T
// (K-chunk = 1024 = 2 batches), then reduces the tile along diagonals
// tau = s - t (mod 1024) into a 1024-bin vector -> partial[blockLinear][tau].
// G is never materialized in HBM.
// Double-buffered LDS (2 x 32 KB), XOR-swizzle byte^=(row&7)<<4, T14 split:
// issue next tile's global loads before the barrier + MFMA phase.
// ---------------------------------------------------------------------------
__global__ __launch_bounds__(256) void gram_fused_kernel(
    const float* __restrict__ q, const float* __restrict__ k,
    float* __restrict__ partial)
{
  __shared__ char smem[65536];   // 2 x (As 16KB + Bs 16KB); reused for reduce

  const int tid = threadIdx.x;
  const int l   = tid & 63;
  const int wid = tid >> 6;
  const int wr  = (wid >> 1) * 64;   // wave row offset in tile
  const int wc  = (wid & 1) * 64;    // wave col offset in tile
  const int s0  = blockIdx.x * 128;
  const int t0  = blockIdx.y * 128;
  const int z   = blockIdx.z;

  // staging ids: it in 0..3, id = it*256+tid -> (row 0..127, c8 0..7)
  int swoff[4];                      // LDS byte offset within a buffer (swizzled)
  size_t agoff[4], bgoff[4];         // global float offsets (row-relative)
  #pragma unroll
  for (int it = 0; it < 4; ++it) {
    const int id  = (it << 8) | tid;
    const int row = id >> 3;
    const int c8  = id & 7;
    swoff[it] = ((row << 7) + (c8 << 4)) ^ ((row & 7) << 4);
    agoff[it] = (size_t)(s0 + row) * HE + c8 * 8;
    bgoff[it] = (size_t)(t0 + row) * HE + c8 * 8;
  }

  f32x4 acc[4][4] = {};
  const int l15 = l & 15;
  const int blk = l >> 4;

  float4 ra0[4], ra1[4], rb0[4], rb1[4];

  // ---- prologue: load+pack+stage tile 0 into buf0 ----
  {
    const size_t boff = (size_t)(z * 2) * L_SEQ * HE;
    #pragma unroll
    for (int it = 0; it < 4; ++it) {
      ra0[it] = *(const float4*)(q + boff + agoff[it]);
      ra1[it] = *(const float4*)(q + boff + agoff[it] + 4);
      rb0[it] = *(const float4*)(k + boff + bgoff[it]);
      rb1[it] = *(const float4*)(k + boff + bgoff[it] + 4);
    }
    #pragma unroll
    for (int it = 0; it < 4; ++it) {
      uint4 pa, pb;
      pa.x = bf2(ra0[it].x, ra0[it].y); pa.y = bf2(ra0[it].z, ra0[it].w);
      pa.z = bf2(ra1[it].x, ra1[it].y); pa.w = bf2(ra1[it].z, ra1[it].w);
      pb.x = bf2(rb0[it].x, rb0[it].y); pb.y = bf2(rb0[it].z, rb0[it].w);
      pb.z = bf2(rb1[it].x, rb1[it].y); pb.w = bf2(rb1[it].z, rb1[it].w);
      *(uint4*)(smem + swoff[it])         = pa;
      *(uint4*)(smem + 16384 + swoff[it]) = pb;
    }
  }

  // ---- main loop: 16 K-steps of 64 ----
  for (int t = 0; t < 16; ++t) {
    // issue next tile's global loads (in flight across barrier + MFMA)
    if (t < 15) {
      const int kt = (t + 1) * 64;
      const size_t boff =
          (size_t)(z * 2 + (kt >> 9)) * L_SEQ * HE + (kt & 511);
      #pragma unroll
      for (int it = 0; it < 4; ++it) {
        ra0[it] = *(const float4*)(q + boff + agoff[it]);
        ra1[it] = *(const float4*)(q + boff + agoff[it] + 4);
        rb0[it] = *(const float4*)(k + boff + bgoff[it]);
        rb1[it] = *(const float4*)(k + boff + bgoff[it] + 4);
      }
    }

    __syncthreads();   // buf[t&1] staged; prior reads of buf[(t+1)&1] done

    const char* rbase = smem + ((t & 1) << 15);
    #pragma unroll
    for (int kk = 0; kk < 2; ++kk) {
      bf16x8 af[4], bfr[4];
      #pragma unroll
      for (int m = 0; m < 4; ++m) {
        const int rowa = wr + m * 16 + l15;
        const int offa = ((rowa << 7) + (kk << 6) + (blk << 4)) ^ ((rowa & 7) << 4);
        af[m] = *(const bf16x8*)(rbase + offa);
        const int rowb = wc + m * 16 + l15;
        const int offb = ((rowb << 7) + (kk << 6) + (blk << 4)) ^ ((rowb & 7) << 4);
        bfr[m] = *(const bf16x8*)(rbase + 16384 + offb);
      }
      #pragma unroll
      for (int m = 0; m < 4; ++m)
        #pragma unroll
        for (int n = 0; n < 4; ++n)
          acc[m][n] = __builtin_amdgcn_mfma_f32_16x16x32_bf16(
              af[m], bfr[n], acc[m][n], 0, 0, 0);
    }

    // pack + stage next tile into the other buffer
    if (t < 15) {
      char* wbase = smem + (((t + 1) & 1) << 15);
      #pragma unroll
      for (int it = 0; it < 4; ++it) {
        uint4 pa, pb;
        pa.x = bf2(ra0[it].x, ra0[it].y); pa.y = bf2(ra0[it].z, ra0[it].w);
        pa.z = bf2(ra1[it].x, ra1[it].y); pa.w = bf2(ra1[it].z, ra1[it].w);
        pb.x = bf2(rb0[it].x, rb0[it].y); pb.y = bf2(rb0[it].z, rb0[it].w);
        pb.z = bf2(rb1[it].x, rb1[it].y); pb.w = bf2(rb1[it].z, rb1[it].w);
        *(uint4*)(wbase + swoff[it])         = pa;
        *(uint4*)(wbase + 16384 + swoff[it]) = pb;
      }
    }
  }

  // ---- fused diagonal reduction (reuse smem) ----
  // Gs: 64x128 fp32 chunk, pad 132 (33792 B). bins: 1024 fp32 at +33792.
  float* Gs   = (float*)smem;
  float* bins = (float*)(smem + 33792);

  __syncthreads();   // all MFMA LDS reads done before overwrite
  for (int i = tid; i < 1024; i += 256) bins[i] = 0.f;

  #pragma unroll
  for (int cc = 0; cc < 2; ++cc) {
    // waves owning rows [64cc, 64cc+64) spill accumulators
    // C/D layout: col = lane&15, row = (lane>>4)*4 + reg  [m89/m91]
    if (wr == cc * 64) {
      #pragma unroll
      for (int m = 0; m < 4; ++m)
        #pragma unroll
        for (int j = 0; j < 4; ++j) {
          const int ds = blk * 4 + m * 16 + j;
          #pragma unroll
          for (int n = 0; n < 4; ++n)
            Gs[ds * 132 + wc + n * 16 + l15] = acc[m][n][j];
        }
    }
    __syncthreads();   // Gs (and bins zero on cc=0) visible

    if (tid < 191) {
      const int o = tid - 127;            // diag offset ds-dt in [-127, 63]
      const int dslo = o > 0 ? o : 0;
      const int dshi = (o + 127 < 63) ? (o + 127) : 63;
      float s = 0.f;
      for (int ds = dslo; ds <= dshi; ++ds) s += Gs[ds * 132 + ds - o];
      const int tau = (s0 - t0 + 64 * cc + o + 2048) & (L_SEQ - 1);
      bins[tau] += s;                     // unique tau per thread per phase
    }
    __syncthreads();
  }

  const int blin = blockIdx.x + 8 * blockIdx.y + 64 * blockIdx.z;
  for (int i = tid; i < 1024; i += 256)
    partial[(size_t)blin * 1024 + i] = bins[i];
}

// ---------------------------------------------------------------------------
// Kernel 2: c[tau] = (1/16384) * sum_{blk<1024} partial[blk][tau]
// grid 64, block 256: block g handles taus [16g, 16g+16).
// ---------------------------------------------------------------------------
__global__ __launch_bounds__(256) void reduce_kernel(
    const float* __restrict__ partial, float* __restrict__ c)
{
  const int tid = threadIdx.x;
  const int g16 = tid & 15;
  const int brow = tid >> 4;
  const int tau = blockIdx.x * 16 + g16;
  float s = 0.f;
  for (int it = 0; it < 64; ++it)
    s += partial[(size_t)(brow + (it << 4)) * 1024 + tau];
  __shared__ float sm[16][17];
  sm[brow][g16] = s;
  __syncthreads();
  if (tid < 16) {
    float t = 0.f;
    #pragma unroll
    for (int r = 0; r < 16; ++r) t += sm[r][tid];
    c[blockIdx.x * 16 + tid] = t * (1.0f / 16384.0f);
  }
}

// ---------------------------------------------------------------------------
// Kernel 3: top-6 (desc, smaller-index tie-break) + softmax. 1 block.
// ---------------------------------------------------------------------------
__global__ __launch_bounds__(256) void topk_kernel(
    const float* __restrict__ c, int* __restrict__ idx_out,
    float* __restrict__ w_out)
{
  __shared__ float vals[L_SEQ];
  __shared__ float rv[256];
  __shared__ int ri[256];
  __shared__ float topv[TOPK];
  __shared__ int topi[TOPK];
  const int tid = threadIdx.x;
  for (int i = tid; i < L_SEQ; i += 256) vals[i] = c[i];
  __syncthreads();

  for (int kk = 0; kk < TOPK; ++kk) {
    float bv = -INFINITY;
    int bi = 1 << 30;
    for (int i = tid; i < L_SEQ; i += 256) {
      const float v = vals[i];
      if (v > bv || (v == bv && i < bi)) { bv = v; bi = i; }
    }
    rv[tid] = bv; ri[tid] = bi;
    __syncthreads();
    for (int off = 128; off > 0; off >>= 1) {
      if (tid < off) {
        const float v2 = rv[tid + off];
        const int i2 = ri[tid + off];
        if (v2 > rv[tid] || (v2 == rv[tid] && i2 < ri[tid])) {
          rv[tid] = v2; ri[tid] = i2;
        }
      }
      __syncthreads();
    }
    if (tid == 0) {
      topv[kk] = rv[0];
      topi[kk] = ri[0];
      vals[ri[0]] = -INFINITY;
    }
    __syncthreads();
  }

  if (tid == 0) {
    const float m = topv[0];
    float e[TOPK], sum = 0.f;
    for (int i = 0; i < TOPK; ++i) { e[i] = expf(topv[i] - m); sum += e[i]; }
    const float inv = 1.0f / sum;
    for (int i = 0; i < TOPK; ++i) { w_out[i] = e[i] * inv; idx_out[i] = topi[i]; }
  }
}

// ---------------------------------------------------------------------------
// Kernel 4: out[b,l,h,e] = sum_k w[k] * v[b,(l+idx[k])%L,h,e]
// ---------------------------------------------------------------------------
__global__ __launch_bounds__(256) void agg_kernel(
    const float* __restrict__ v, const int* __restrict__ idx,
    const float* __restrict__ w, float4* __restrict__ out)
{
  __shared__ int sidx[TOPK];
  __shared__ float sw[TOPK];
  if (threadIdx.x < TOPK) {
    sidx[threadIdx.x] = idx[threadIdx.x];
    sw[threadIdx.x] = w[threadIdx.x];
  }
  __syncthreads();

  const int i = blockIdx.x * 256 + threadIdx.x;   // 0 .. 2^22-1
  const int he4 = i & 127;                        // 512/4
  const int l = (i >> 7) & (L_SEQ - 1);
  const int b = i >> 17;
  const float4* vb = (const float4*)v + (size_t)b * (L_SEQ * 128);

  float4 acc = make_float4(0.f, 0.f, 0.f, 0.f);
  #pragma unroll
  for (int kk = 0; kk < TOPK; ++kk) {
    const int src = (l + sidx[kk]) & (L_SEQ - 1);
    const float4 vv = vb[(size_t)src * 128 + he4];
    const float wk = sw[kk];
    acc.x += wk * vv.x; acc.y += wk * vv.y;
    acc.z += wk * vv.z; acc.w += wk * vv.w;
  }
  out[i] = acc;
}

// ---------------------------------------------------------------------------
extern "C" void kernel_launch(void* const* d_in, const int* in_sizes, int n_in,
                              void* d_out, int out_size, void* d_ws, size_t ws_size,
                              hipStream_t stream) {
  const float* q = (const float*)d_in[0];
  const float* k = (const float*)d_in[1];
  const float* v = (const float*)d_in[2];
  // d_in[3] = attn_mask (scalar 0) -- unused

  float* out = (float*)d_out;
  // partial diag bins: 1024 blocks x 1024 taus x 4B = 4 MB staged at the
  // front of d_out; fully consumed by reduce_kernel before agg overwrites.
  float* partial = out;

  float* c = (float*)d_ws;                              // 1024 floats
  int* idxp = (int*)((char*)d_ws + 4096);               // 6 ints
  float* wp = (float*)((char*)d_ws + 4096 + 64);        // 6 floats

  dim3 gGram(L_SEQ / 128, L_SEQ / 128, NZ);
  gram_fused_kernel<<<gGram, 256, 0, stream>>>(q, k, partial);
  reduce_kernel<<<64, 256, 0, stream>>>(partial, c);
  topk_kernel<<<1, 256, 0, stream>>>(c, idxp, wp);
  agg_kernel<<<(L_SEQ * NBATCH * 128) / 256, 256, 0, stream>>>(v, idxp, wp,
                                                               (float4*)out);
}

// Round 4
// 134.096 us; speedup vs baseline: 5.0354x; 1.3572x over previous
//
#include <hip/hip_runtime.h>
#include <math.h>

#define L_SEQ 1024
#define HE 512          // H*E
#define NBATCH 32
#define TOPK 6
#define NZ 32           // K-split: one batch (K-chunk of 512) per z

using bf16x8 = __attribute__((ext_vector_type(8))) short;
using f32x4  = __attribute__((ext_vector_type(4))) float;
using f32x2v = __attribute__((ext_vector_type(2))) float;
using bfx2v  = __attribute__((ext_vector_type(2))) __bf16;

// pack two fp32 -> two bf16 (RNE) in one uint; lowers to v_cvt_pk_bf16_f32
__device__ __forceinline__ unsigned int bf2(float lo, float hi) {
  f32x2v f; f[0] = lo; f[1] = hi;
  bfx2v h = __builtin_convertvector(f, bfx2v);
  return *(unsigned int*)&h;
}

// ---------------------------------------------------------------------------
// Kernel 1: fused partial-Gram (bf16 MFMA) + per-block diagonal reduction.
// Block (x,y,z): 256x256 tile of Gz = q_batch . k_batch^T (K-chunk = 512 =
// one batch), reduced along diagonals tau = s - t (mod 1024) into
// partial[blin][tau]. G never touches HBM.
// 8 waves (2M x 4N), per-wave 128x64 output, BK=64, single-buffered LDS with
// XOR swizzle byte^=(row&7)<<4, 2-barrier K-loop (proven round-2 ordering).
// ---------------------------------------------------------------------------
__global__ __launch_bounds__(512, 2) void gram_fused_kernel(
    const float* __restrict__ q, const float* __restrict__ k,
    float* __restrict__ partial)
{
  __shared__ char smem[71680];   // staging 64 KB; tail Gs 66 KB + bins 4 KB
  char* As = smem;               // 256x64 bf16, swizzled (32 KB)
  char* Bs = smem + 32768;       // 256x64 bf16, swizzled (32 KB)

  const int tid = threadIdx.x;       // 0..511
  const int l   = tid & 63;
  const int wid = tid >> 6;          // 0..7
  const int wrm = (wid >> 2) * 128;  // wave row offset (0 / 128)
  const int wcn = (wid & 3) * 64;    // wave col offset (0/64/128/192)
  const int s0  = blockIdx.x * 256;
  const int t0  = blockIdx.y * 256;
  const int z   = blockIdx.z;        // batch index

  // staging chunks: it in 0..3, id = it*512+tid -> (row 0..255, c8 0..7)
  int swoff[4];
  size_t agoff[4], bgoff[4];
  #pragma unroll
  for (int it = 0; it < 4; ++it) {
    const int id  = (it << 9) | tid;
    const int row = id >> 3;
    const int c8  = id & 7;
    swoff[it] = ((row << 7) + (c8 << 4)) ^ ((row & 7) << 4);
    agoff[it] = (size_t)(s0 + row) * HE + c8 * 8;
    bgoff[it] = (size_t)(t0 + row) * HE + c8 * 8;
  }
  const size_t zbase = (size_t)z * L_SEQ * HE;

  f32x4 acc[8][4] = {};
  const int l15 = l & 15;
  const int blk = l >> 4;

  for (int t = 0; t < 8; ++t) {      // K per block = 512, BK = 64
    const size_t boff = zbase + t * 64;

    float4 ra0[4], ra1[4], rb0[4], rb1[4];
    #pragma unroll
    for (int it = 0; it < 4; ++it) {
      ra0[it] = *(const float4*)(q + boff + agoff[it]);
      ra1[it] = *(const float4*)(q + boff + agoff[it] + 4);
      rb0[it] = *(const float4*)(k + boff + bgoff[it]);
      rb1[it] = *(const float4*)(k + boff + bgoff[it] + 4);
    }

    __syncthreads();   // previous K-step's LDS reads done
    #pragma unroll
    for (int it = 0; it < 4; ++it) {
      uint4 pa, pb;
      pa.x = bf2(ra0[it].x, ra0[it].y); pa.y = bf2(ra0[it].z, ra0[it].w);
      pa.z = bf2(ra1[it].x, ra1[it].y); pa.w = bf2(ra1[it].z, ra1[it].w);
      pb.x = bf2(rb0[it].x, rb0[it].y); pb.y = bf2(rb0[it].z, rb0[it].w);
      pb.z = bf2(rb1[it].x, rb1[it].y); pb.w = bf2(rb1[it].z, rb1[it].w);
      *(uint4*)(As + swoff[it]) = pa;
      *(uint4*)(Bs + swoff[it]) = pb;
    }
    __syncthreads();   // tile staged

    #pragma unroll
    for (int kk = 0; kk < 2; ++kk) {
      bf16x8 bfr[4];
      #pragma unroll
      for (int n = 0; n < 4; ++n) {
        const int rowb = wcn + n * 16 + l15;
        const int offb = ((rowb << 7) + (kk << 6) + (blk << 4)) ^ ((rowb & 7) << 4);
        bfr[n] = *(const bf16x8*)(Bs + offb);
      }
      #pragma unroll
      for (int mh = 0; mh < 2; ++mh) {   // split A-frags: cap live VGPRs
        bf16x8 af[4];
        #pragma unroll
        for (int j = 0; j < 4; ++j) {
          const int rowa = wrm + (mh * 4 + j) * 16 + l15;
          const int offa = ((rowa << 7) + (kk << 6) + (blk << 4)) ^ ((rowa & 7) << 4);
          af[j] = *(const bf16x8*)(As + offa);
        }
        #pragma unroll
        for (int j = 0; j < 4; ++j)
          #pragma unroll
          for (int n = 0; n < 4; ++n)
            acc[mh * 4 + j][n] = __builtin_amdgcn_mfma_f32_16x16x32_bf16(
                af[j], bfr[n], acc[mh * 4 + j][n], 0, 0, 0);
      }
    }
  }

  // ---- fused diagonal reduction (reuse smem) ----
  // Gs: 64 x 256 fp32 chunk, stride 264 (264%32==8 -> 2-way max on spill).
  // bins: 1024 fp32 at byte 67584.
  float* Gs   = (float*)smem;
  float* bins = (float*)(smem + 67584);

  __syncthreads();   // all MFMA LDS reads done before overwrite
  for (int i = tid; i < 1024; i += 512) bins[i] = 0.f;

  #pragma unroll
  for (int cc = 0; cc < 4; ++cc) {   // row-chunk [64cc, 64cc+64)
    __syncthreads();                 // bins zeroed / previous diag reads done

    // spill: waves whose wrm covers this chunk
    // C/D layout: col = lane&15, row = (lane>>4)*4 + reg  [m89/m91]
    if ((wid >> 2) == (cc >> 1)) {
      #pragma unroll
      for (int mp = 0; mp < 4; ++mp) {
        const int m = (cc & 1) * 4 + mp;
        #pragma unroll
        for (int j = 0; j < 4; ++j) {
          const int ds = mp * 16 + blk * 4 + j;
          #pragma unroll
          for (int n = 0; n < 4; ++n)
            Gs[ds * 264 + wcn + n * 16 + l15] = acc[m][n][j];
        }
      }
    }
    __syncthreads();                 // Gs visible

    if (tid < 319) {
      const int o = tid - 255;       // diag offset ds-dt in [-255, 63]
      float s = 0.f;
      #pragma unroll
      for (int i = 0; i < 64; ++i) { // fixed-trip, predicated -> pipelined
        const int dt = i - o;
        const bool ok = (dt >= 0) && (dt < 256);
        const int dtc = ok ? dt : 0;
        const float v = Gs[i * 264 + dtc];
        s += ok ? v : 0.f;
      }
      const int tau = (s0 - t0 + 64 * cc + o + 4096) & (L_SEQ - 1);
      bins[tau] += s;                // unique tau per thread per phase
    }
  }
  __syncthreads();

  const int blin = blockIdx.x + 4 * blockIdx.y + 16 * blockIdx.z;  // 0..511
  for (int i = tid; i < 1024; i += 512)
    partial[(size_t)blin * 1024 + i] = bins[i];
}

// ---------------------------------------------------------------------------
// Kernel 2: c[tau] = (1/16384) * sum_{blk<512} partial[blk][tau]
// grid 64, block 256: block g handles taus [16g, 16g+16).
// ---------------------------------------------------------------------------
__global__ __launch_bounds__(256) void reduce_kernel(
    const float* __restrict__ partial, float* __restrict__ c)
{
  const int tid = threadIdx.x;
  const int g16 = tid & 15;
  const int brow = tid >> 4;
  const int tau = blockIdx.x * 16 + g16;
  float s = 0.f;
  for (int it = 0; it < 32; ++it)
    s += partial[(size_t)(brow + (it << 4)) * 1024 + tau];
  __shared__ float sm[16][17];
  sm[brow][g16] = s;
  __syncthreads();
  if (tid < 16) {
    float t = 0.f;
    #pragma unroll
    for (int r = 0; r < 16; ++r) t += sm[r][tid];
    c[blockIdx.x * 16 + tid] = t * (1.0f / 16384.0f);
  }
}

// ---------------------------------------------------------------------------
// Kernel 3: top-6 (desc, smaller-index tie-break) + softmax. 1 block.
// ---------------------------------------------------------------------------
__global__ __launch_bounds__(256) void topk_kernel(
    const float* __restrict__ c, int* __restrict__ idx_out,
    float* __restrict__ w_out)
{
  __shared__ float vals[L_SEQ];
  __shared__ float rv[256];
  __shared__ int ri[256];
  __shared__ float topv[TOPK];
  __shared__ int topi[TOPK];
  const int tid = threadIdx.x;
  for (int i = tid; i < L_SEQ; i += 256) vals[i] = c[i];
  __syncthreads();

  for (int kk = 0; kk < TOPK; ++kk) {
    float bv = -INFINITY;
    int bi = 1 << 30;
    for (int i = tid; i < L_SEQ; i += 256) {
      const float v = vals[i];
      if (v > bv || (v == bv && i < bi)) { bv = v; bi = i; }
    }
    rv[tid] = bv; ri[tid] = bi;
    __syncthreads();
    for (int off = 128; off > 0; off >>= 1) {
      if (tid < off) {
        const float v2 = rv[tid + off];
        const int i2 = ri[tid + off];
        if (v2 > rv[tid] || (v2 == rv[tid] && i2 < ri[tid])) {
          rv[tid] = v2; ri[tid] = i2;
        }
      }
      __syncthreads();
    }
    if (tid == 0) {
      topv[kk] = rv[0];
      topi[kk] = ri[0];
      vals[ri[0]] = -INFINITY;
    }
    __syncthreads();
  }

  if (tid == 0) {
    const float m = topv[0];
    float e[TOPK], sum = 0.f;
    for (int i = 0; i < TOPK; ++i) { e[i] = expf(topv[i] - m); sum += e[i]; }
    const float inv = 1.0f / sum;
    for (int i = 0; i < TOPK; ++i) { w_out[i] = e[i] * inv; idx_out[i] = topi[i]; }
  }
}

// ---------------------------------------------------------------------------
// Kernel 4: out[b,l,h,e] = sum_k w[k] * v[b,(l+idx[k])%L,h,e]
// ---------------------------------------------------------------------------
__global__ __launch_bounds__(256) void agg_kernel(
    const float* __restrict__ v, const int* __restrict__ idx,
    const float* __restrict__ w, float4* __restrict__ out)
{
  __shared__ int sidx[TOPK];
  __shared__ float sw[TOPK];
  if (threadIdx.x < TOPK) {
    sidx[threadIdx.x] = idx[threadIdx.x];
    sw[threadIdx.x] = w[threadIdx.x];
  }
  __syncthreads();

  const int i = blockIdx.x * 256 + threadIdx.x;   // 0 .. 2^22-1
  const int he4 = i & 127;                        // 512/4
  const int l = (i >> 7) & (L_SEQ - 1);
  const int b = i >> 17;
  const float4* vb = (const float4*)v + (size_t)b * (L_SEQ * 128);

  float4 acc = make_float4(0.f, 0.f, 0.f, 0.f);
  #pragma unroll
  for (int kk = 0; kk < TOPK; ++kk) {
    const int src = (l + sidx[kk]) & (L_SEQ - 1);
    const float4 vv = vb[(size_t)src * 128 + he4];
    const float wk = sw[kk];
    acc.x += wk * vv.x; acc.y += wk * vv.y;
    acc.z += wk * vv.z; acc.w += wk * vv.w;
  }
  out[i] = acc;
}

// ---------------------------------------------------------------------------
extern "C" void kernel_launch(void* const* d_in, const int* in_sizes, int n_in,
                              void* d_out, int out_size, void* d_ws, size_t ws_size,
                              hipStream_t stream) {
  const float* q = (const float*)d_in[0];
  const float* k = (const float*)d_in[1];
  const float* v = (const float*)d_in[2];
  // d_in[3] = attn_mask (scalar 0) -- unused

  float* out = (float*)d_out;
  // partial diag bins: 512 blocks x 1024 taus x 4B = 2 MB at the front of
  // d_out; fully consumed by reduce_kernel before agg overwrites d_out.
  float* partial = out;

  float* c = (float*)d_ws;                              // 1024 floats
  int* idxp = (int*)((char*)d_ws + 4096);               // 6 ints
  float* wp = (float*)((char*)d_ws + 4096 + 64);        // 6 floats

  dim3 gGram(L_SEQ / 256, L_SEQ / 256, NZ);
  gram_fused_kernel<<<gGram, 512, 0, stream>>>(q, k, partial);
  reduce_kernel<<<64, 256, 0, stream>>>(partial, c);
  topk_kernel<<<1, 256, 0, stream>>>(c, idxp, wp);
  agg_kernel<<<(L_SEQ * NBATCH * 128) / 256, 256, 0, stream>>>(v, idxp, wp,
                                                               (float4*)out);
}

// Round 5
// 122.304 us; speedup vs baseline: 5.5208x; 1.0964x over previous
//
#include <hip/hip_runtime.h>
#include <math.h>

#define L_SEQ 1024
#define HE 512          // H*E
#define NBATCH 32
#define TOPK 6
#define NZ 16           // K-split: 2 batches = K-chunk of 1024 per z

using bf16x8 = __attribute__((ext_vector_type(8))) short;
using f32x4  = __attribute__((ext_vector_type(4))) float;
using f32x2v = __attribute__((ext_vector_type(2))) float;
using bfx2v  = __attribute__((ext_vector_type(2))) __bf16;

// pack two fp32 -> two bf16 (RNE) in one uint; lowers to v_cvt_pk_bf16_f32
__device__ __forceinline__ unsigned int bf2(float lo, float hi) {
  f32x2v f; f[0] = lo; f[1] = hi;
  bfx2v h = __builtin_convertvector(f, bfx2v);
  return *(unsigned int*)&h;
}

// ---------------------------------------------------------------------------
// Kernel 1: fused partial-Gram (bf16 MFMA) + per-block diagonal reduction.
// Block (x,y,z): 256x256 tile of Gz = q . k^T over K-chunk 1024 (batches
// 2z, 2z+1), reduced along diagonals tau = s - t (mod 1024) into
// partial[blin][tau]. G never touches HBM.
// 8 waves (2M x 4N), per-wave 128x64, BK=64, DOUBLE-buffered swizzled LDS,
// T14 async-split: issue next tile's loads -> MFMA(cur) -> pack+write(next)
// -> single barrier. Load latency hides under the 64-MFMA phase.
// ---------------------------------------------------------------------------
__global__ __launch_bounds__(512, 2) void gram_fused_kernel(
    const float* __restrict__ q, const float* __restrict__ k,
    float* __restrict__ partial)
{
  __shared__ char smem[131072];  // 2 x (As 32KB + Bs 32KB); tail reuses it

  const int tid = threadIdx.x;       // 0..511
  const int l   = tid & 63;
  const int wid = tid >> 6;          // 0..7
  const int wrm = (wid >> 2) * 128;  // wave row offset (0 / 128)
  const int wcn = (wid & 3) * 64;    // wave col offset (0/64/128/192)
  const int s0  = blockIdx.x * 256;
  const int t0  = blockIdx.y * 256;
  const int z   = blockIdx.z;        // batch pair index

  // staging chunks: it in 0..3, id = it*512+tid -> (row 0..255, c8 0..7)
  int swoff[4];
  unsigned int agoff[4], bgoff[4];   // 32-bit global float offsets
  #pragma unroll
  for (int it = 0; it < 4; ++it) {
    const int id  = (it << 9) | tid;
    const int row = id >> 3;
    const int c8  = id & 7;
    swoff[it] = ((row << 7) + (c8 << 4)) ^ ((row & 7) << 4);
    agoff[it] = (unsigned int)(s0 + row) * HE + c8 * 8;
    bgoff[it] = (unsigned int)(t0 + row) * HE + c8 * 8;
  }

  f32x4 acc[8][4] = {};
  const int l15 = l & 15;
  const int blk = l >> 4;

  float4 ra0[4], ra1[4], rb0[4], rb1[4];

  // ---- prologue: load + pack + stage tile 0 into buf0 ----
  {
    const unsigned int boff = (unsigned int)(z * 2) * L_SEQ * HE;
    #pragma unroll
    for (int it = 0; it < 4; ++it) {
      ra0[it] = *(const float4*)(q + boff + agoff[it]);
      ra1[it] = *(const float4*)(q + boff + agoff[it] + 4);
      rb0[it] = *(const float4*)(k + boff + bgoff[it]);
      rb1[it] = *(const float4*)(k + boff + bgoff[it] + 4);
    }
    #pragma unroll
    for (int it = 0; it < 4; ++it) {
      uint4 pa, pb;
      pa.x = bf2(ra0[it].x, ra0[it].y); pa.y = bf2(ra0[it].z, ra0[it].w);
      pa.z = bf2(ra1[it].x, ra1[it].y); pa.w = bf2(ra1[it].z, ra1[it].w);
      pb.x = bf2(rb0[it].x, rb0[it].y); pb.y = bf2(rb0[it].z, rb0[it].w);
      pb.z = bf2(rb1[it].x, rb1[it].y); pb.w = bf2(rb1[it].z, rb1[it].w);
      *(uint4*)(smem + swoff[it])         = pa;
      *(uint4*)(smem + 32768 + swoff[it]) = pb;
    }
  }
  __syncthreads();

  // ---- main loop: 16 K-steps of 64, double-buffered ----
  for (int t = 0; t < 16; ++t) {
    // 1) issue next tile's global loads (in flight during MFMA phase)
    if (t < 15) {
      const int tn = t + 1;
      const unsigned int boff =
          (unsigned int)(z * 2 + (tn >> 3)) * L_SEQ * HE + (tn & 7) * 64;
      #pragma unroll
      for (int it = 0; it < 4; ++it) {
        ra0[it] = *(const float4*)(q + boff + agoff[it]);
        ra1[it] = *(const float4*)(q + boff + agoff[it] + 4);
        rb0[it] = *(const float4*)(k + boff + bgoff[it]);
        rb1[it] = *(const float4*)(k + boff + bgoff[it] + 4);
      }
    }

    // 2) MFMA phase on buf[t&1]
    const char* rbase = smem + ((t & 1) << 16);
    __builtin_amdgcn_s_setprio(1);
    #pragma unroll
    for (int kk = 0; kk < 2; ++kk) {
      bf16x8 bfr[4];
      #pragma unroll
      for (int n = 0; n < 4; ++n) {
        const int rowb = wcn + n * 16 + l15;
        const int offb = ((rowb << 7) + (kk << 6) + (blk << 4)) ^ ((rowb & 7) << 4);
        bfr[n] = *(const bf16x8*)(rbase + 32768 + offb);
      }
      #pragma unroll
      for (int mh = 0; mh < 2; ++mh) {   // split A-frags: cap live VGPRs
        bf16x8 af[4];
        #pragma unroll
        for (int j = 0; j < 4; ++j) {
          const int rowa = wrm + (mh * 4 + j) * 16 + l15;
          const int offa = ((rowa << 7) + (kk << 6) + (blk << 4)) ^ ((rowa & 7) << 4);
          af[j] = *(const bf16x8*)(rbase + offa);
        }
        #pragma unroll
        for (int j = 0; j < 4; ++j)
          #pragma unroll
          for (int n = 0; n < 4; ++n)
            acc[mh * 4 + j][n] = __builtin_amdgcn_mfma_f32_16x16x32_bf16(
                af[j], bfr[n], acc[mh * 4 + j][n], 0, 0, 0);
      }
    }
    __builtin_amdgcn_s_setprio(0);

    // 3) pack + stage next tile into the other buffer
    if (t < 15) {
      char* wbase = smem + (((t + 1) & 1) << 16);
      #pragma unroll
      for (int it = 0; it < 4; ++it) {
        uint4 pa, pb;
        pa.x = bf2(ra0[it].x, ra0[it].y); pa.y = bf2(ra0[it].z, ra0[it].w);
        pa.z = bf2(ra1[it].x, ra1[it].y); pa.w = bf2(ra1[it].z, ra1[it].w);
        pb.x = bf2(rb0[it].x, rb0[it].y); pb.y = bf2(rb0[it].z, rb0[it].w);
        pb.z = bf2(rb1[it].x, rb1[it].y); pb.w = bf2(rb1[it].z, rb1[it].w);
        *(uint4*)(wbase + swoff[it])         = pa;
        *(uint4*)(wbase + 32768 + swoff[it]) = pb;
      }
    }
    __syncthreads();
  }

  // ---- fused diagonal reduction (reuse smem) ----
  // Gs: 64 x 256 fp32 chunk, stride 264 (2-way max on spill).
  // bins: 1024 fp32 at byte 67584.
  float* Gs   = (float*)smem;
  float* bins = (float*)(smem + 67584);

  for (int i = tid; i < 1024; i += 512) bins[i] = 0.f;

  #pragma unroll
  for (int cc = 0; cc < 4; ++cc) {   // row-chunk [64cc, 64cc+64)
    __syncthreads();                 // bins zeroed / previous phase done

    // spill: waves whose wrm covers this chunk
    // C/D layout: col = lane&15, row = (lane>>4)*4 + reg  [m89/m91]
    if ((wid >> 2) == (cc >> 1)) {
      #pragma unroll
      for (int mp = 0; mp < 4; ++mp) {
        const int m = (cc & 1) * 4 + mp;
        #pragma unroll
        for (int j = 0; j < 4; ++j) {
          const int ds = mp * 16 + blk * 4 + j;
          #pragma unroll
          for (int n = 0; n < 4; ++n)
            Gs[ds * 264 + wcn + n * 16 + l15] = acc[m][n][j];
        }
      }
    }
    __syncthreads();                 // Gs visible

    if (tid < 319) {
      const int o = tid - 255;       // diag offset ds-dt in [-255, 63]
      float s = 0.f;
      #pragma unroll
      for (int i = 0; i < 64; ++i) { // fixed-trip, predicated -> pipelined
        const int dt = i - o;
        const bool ok = (dt >= 0) && (dt < 256);
        const int dtc = ok ? dt : 0;
        const float v = Gs[i * 264 + dtc];
        s += ok ? v : 0.f;
      }
      const int tau = (s0 - t0 + 64 * cc + o + 4096) & (L_SEQ - 1);
      bins[tau] += s;                // unique tau per thread per phase
    }
  }
  __syncthreads();

  const int blin = blockIdx.x + 4 * blockIdx.y + 16 * blockIdx.z;  // 0..255
  for (int i = tid; i < 1024; i += 512)
    partial[(size_t)blin * 1024 + i] = bins[i];
}

// ---------------------------------------------------------------------------
// Kernel 2: c[tau] = (1/16384) * sum_{blk<256} partial[blk][tau]
// grid 64, block 256: block g handles taus [16g, 16g+16).
// ---------------------------------------------------------------------------
__global__ __launch_bounds__(256) void reduce_kernel(
    const float* __restrict__ partial, float* __restrict__ c)
{
  const int tid = threadIdx.x;
  const int g16 = tid & 15;
  const int brow = tid >> 4;
  const int tau = blockIdx.x * 16 + g16;
  float s = 0.f;
  for (int it = 0; it < 16; ++it)
    s += partial[(size_t)(brow + (it << 4)) * 1024 + tau];
  __shared__ float sm[16][17];
  sm[brow][g16] = s;
  __syncthreads();
  if (tid < 16) {
    float t = 0.f;
    #pragma unroll
    for (int r = 0; r < 16; ++r) t += sm[r][tid];
    c[blockIdx.x * 16 + tid] = t * (1.0f / 16384.0f);
  }
}

// ---------------------------------------------------------------------------
// Kernel 3: top-6 (desc, smaller-index tie-break) + softmax. 1 block.
// ---------------------------------------------------------------------------
__global__ __launch_bounds__(256) void topk_kernel(
    const float* __restrict__ c, int* __restrict__ idx_out,
    float* __restrict__ w_out)
{
  __shared__ float vals[L_SEQ];
  __shared__ float rv[256];
  __shared__ int ri[256];
  __shared__ float topv[TOPK];
  __shared__ int topi[TOPK];
  const int tid = threadIdx.x;
  for (int i = tid; i < L_SEQ; i += 256) vals[i] = c[i];
  __syncthreads();

  for (int kk = 0; kk < TOPK; ++kk) {
    float bv = -INFINITY;
    int bi = 1 << 30;
    for (int i = tid; i < L_SEQ; i += 256) {
      const float v = vals[i];
      if (v > bv || (v == bv && i < bi)) { bv = v; bi = i; }
    }
    rv[tid] = bv; ri[tid] = bi;
    __syncthreads();
    for (int off = 128; off > 0; off >>= 1) {
      if (tid < off) {
        const float v2 = rv[tid + off];
        const int i2 = ri[tid + off];
        if (v2 > rv[tid] || (v2 == rv[tid] && i2 < ri[tid])) {
          rv[tid] = v2; ri[tid] = i2;
        }
      }
      __syncthreads();
    }
    if (tid == 0) {
      topv[kk] = rv[0];
      topi[kk] = ri[0];
      vals[ri[0]] = -INFINITY;
    }
    __syncthreads();
  }

  if (tid == 0) {
    const float m = topv[0];
    float e[TOPK], sum = 0.f;
    for (int i = 0; i < TOPK; ++i) { e[i] = expf(topv[i] - m); sum += e[i]; }
    const float inv = 1.0f / sum;
    for (int i = 0; i < TOPK; ++i) { w_out[i] = e[i] * inv; idx_out[i] = topi[i]; }
  }
}

// ---------------------------------------------------------------------------
// Kernel 4: out[b,l,h,e] = sum_k w[k] * v[b,(l+idx[k])%L,h,e]
// ---------------------------------------------------------------------------
__global__ __launch_bounds__(256) void agg_kernel(
    const float* __restrict__ v, const int* __restrict__ idx,
    const float* __restrict__ w, float4* __restrict__ out)
{
  __shared__ int sidx[TOPK];
  __shared__ float sw[TOPK];
  if (threadIdx.x < TOPK) {
    sidx[threadIdx.x] = idx[threadIdx.x];
    sw[threadIdx.x] = w[threadIdx.x];
  }
  __syncthreads();

  const int i = blockIdx.x * 256 + threadIdx.x;   // 0 .. 2^22-1
  const int he4 = i & 127;                        // 512/4
  const int l = (i >> 7) & (L_SEQ - 1);
  const int b = i >> 17;
  const float4* vb = (const float4*)v + (size_t)b * (L_SEQ * 128);

  float4 acc = make_float4(0.f, 0.f, 0.f, 0.f);
  #pragma unroll
  for (int kk = 0; kk < TOPK; ++kk) {
    const int src = (l + sidx[kk]) & (L_SEQ - 1);
    const float4 vv = vb[(size_t)src * 128 + he4];
    const float wk = sw[kk];
    acc.x += wk * vv.x; acc.y += wk * vv.y;
    acc.z += wk * vv.z; acc.w += wk * vv.w;
  }
  out[i] = acc;
}

// ---------------------------------------------------------------------------
extern "C" void kernel_launch(void* const* d_in, const int* in_sizes, int n_in,
                              void* d_out, int out_size, void* d_ws, size_t ws_size,
                              hipStream_t stream) {
  const float* q = (const float*)d_in[0];
  const float* k = (const float*)d_in[1];
  const float* v = (const float*)d_in[2];
  // d_in[3] = attn_mask (scalar 0) -- unused

  float* out = (float*)d_out;
  // partial diag bins: 256 blocks x 1024 taus x 4B = 1 MB at the front of
  // d_out; fully consumed by reduce_kernel before agg overwrites d_out.
  float* partial = out;

  float* c = (float*)d_ws;                              // 1024 floats
  int* idxp = (int*)((char*)d_ws + 4096);               // 6 ints
  float* wp = (float*)((char*)d_ws + 4096 + 64);        // 6 floats

  dim3 gGram(L_SEQ / 256, L_SEQ / 256, NZ);
  gram_fused_kernel<<<gGram, 512, 0, stream>>>(q, k, partial);
  reduce_kernel<<<64, 256, 0, stream>>>(partial, c);
  topk_kernel<<<1, 256, 0, stream>>>(c, idxp, wp);
  agg_kernel<<<(L_SEQ * NBATCH * 128) / 256, 256, 0, stream>>>(v, idxp, wp,
                                                               (float4*)out);
}